// Round 14
// baseline (431.620 us; speedup 1.0000x reference)
//
#include <hip/hip_runtime.h>
#include <hip/hip_bf16.h>
#include <stdint.h>
#include <math.h>

#define NR 16384
#define DIM 768
#define KEPS 1e-8f

#define BM 128          // tile edge
#define NB (NR / BM)    // 128 row/col panels
#define NQ (DIM / 16)   // 48 16B chunks per row
#define NTILES (NB * (NB + 1) / 2)   // 8256 upper-triangle tiles

typedef __attribute__((ext_vector_type(4))) float f32x4;
typedef __attribute__((ext_vector_type(2))) long long2_t;

__device__ inline uint32_t fkey(float f) {
    union { float f; uint32_t u; } v; v.f = f;
    return (v.u & 0x80000000u) ? ~v.u : (v.u | 0x80000000u);
}

__device__ inline unsigned long long pack_vc(float v, int c) {
    return ((unsigned long long)fkey(v) << 32) | (unsigned)c;
}

// fp32 -> OCP e4m3fn (selection only; refine pass recomputes exact fp32)
__device__ inline uint8_t f2fp8(float f) {
    union { float f; uint32_t u; } v; v.f = f;
    const uint8_t s = (uint8_t)((v.u >> 24) & 0x80u);
    float a = fabsf(f);
    if (a >= 448.0f) return s | 0x7E;
    if (a < 0.015625f) {
        int q = (int)rintf(a * 512.0f);
        if (q >= 8) return s | 0x08;
        return s | (uint8_t)q;
    }
    int ex; float m = frexpf(a, &ex);
    int E = ex + 6;
    int frac = (int)rintf(m * 16.0f - 8.0f);
    if (frac >= 8) { frac = 0; ++E; if (E > 15) return s | 0x7E; }
    return s | (uint8_t)(E << 3) | (uint8_t)frac;
}

// ---- Kernel 1: L2-normalize -> fp8, panel-blocked TRANSPOSED, coalesced -----
// One block per 64 rows. Phase 1: each wave normalizes+quantizes 16 rows into
// padded LDS [64][776] (776%8==0 for uint2 reads; phase-1 writes conflict-free,
// phase-2 reads 4-way worst case). Phase 2: write XnT[p][q][rip] with lanes =
// consecutive rows -> 1KB contiguous stores (R13's 16B/2KB-stride scatter fix).
// ks-pairing permutation kept: chunk q holds orig bytes (blk*64+h*8..+8) and
// (blk*64+32+h*8..+8), blk=q>>2, h=q&3.
__global__ __launch_bounds__(256) void k_norm(const float* __restrict__ X,
                                              uint8_t* __restrict__ XnT,
                                              float* __restrict__ norms) {
    __shared__ uint8_t buf[64][776];
    const int wid = threadIdx.x >> 6, lane = threadIdx.x & 63;
#pragma unroll
    for (int i = 0; i < 16; ++i) {
        const int rloc = wid * 16 + i;
        const int grow = blockIdx.x * 64 + rloc;
        const float4* xr = (const float4*)(X + (size_t)grow * DIM) + lane * 3;
        float4 a = xr[0], b = xr[1], c = xr[2];
        float s = a.x*a.x + a.y*a.y + a.z*a.z + a.w*a.w
                + b.x*b.x + b.y*b.y + b.z*b.z + b.w*b.w
                + c.x*c.x + c.y*c.y + c.z*c.z + c.w*c.w;
#pragma unroll
        for (int m = 32; m >= 1; m >>= 1) s += __shfl_xor(s, m);
        const float n = sqrtf(s);
        if (lane == 0) norms[grow] = n;
        const float rn = 1.0f / fmaxf(n, KEPS);
        float v[12] = {a.x,a.y,a.z,a.w,b.x,b.y,b.z,b.w,c.x,c.y,c.z,c.w};
        uint8_t q[12];
#pragma unroll
        for (int k = 0; k < 12; ++k) q[k] = f2fp8(v[k] * rn);
        uint32_t* lb = (uint32_t*)&buf[rloc][lane * 12];
        lb[0] = (uint32_t)q[0] | ((uint32_t)q[1] << 8) | ((uint32_t)q[2]  << 16) | ((uint32_t)q[3]  << 24);
        lb[1] = (uint32_t)q[4] | ((uint32_t)q[5] << 8) | ((uint32_t)q[6]  << 16) | ((uint32_t)q[7]  << 24);
        lb[2] = (uint32_t)q[8] | ((uint32_t)q[9] << 8) | ((uint32_t)q[10] << 16) | ((uint32_t)q[11] << 24);
    }
    __syncthreads();
    const int r  = threadIdx.x & 63;
    const int qg = threadIdx.x >> 6;
    const int p   = blockIdx.x >> 1;
    const int rip = (blockIdx.x & 1) * 64 + r;
#pragma unroll
    for (int i = 0; i < 12; ++i) {
        const int q = i * 4 + qg;
        const int blk = q >> 2, h = q & 3;
        const uint2 lo = *(const uint2*)&buf[r][blk * 64 + h * 8];
        const uint2 hi = *(const uint2*)&buf[r][blk * 64 + 32 + h * 8];
        const size_t off = ((size_t)p * NQ * 128 + (size_t)q * 128 + rip) * 16;
        *(uint4*)(XnT + off) = make_uint4(lo.x, lo.y, hi.x, hi.y);
    }
}

// ---------------- Kernel 1b: init (value, index) max keys --------------------
__global__ __launch_bounds__(256) void k_init(unsigned long long* __restrict__ nn64) {
    nn64[blockIdx.x * 256 + threadIdx.x] = pack_vc(-2.0f, 0);
}

// 32-MFMA step on one fragment buffer (inlined; static indices -> registers)
__device__ __forceinline__ void mstep(f32x4 (&acc)[4][4],
                                      long2_t a0, long2_t a1, long2_t a2, long2_t a3,
                                      long2_t b0, long2_t b1, long2_t b2, long2_t b3) {
    const long ax[4] = {a0.x, a1.x, a2.x, a3.x};
    const long ay[4] = {a0.y, a1.y, a2.y, a3.y};
    const long bx[4] = {b0.x, b1.x, b2.x, b3.x};
    const long by[4] = {b0.y, b1.y, b2.y, b3.y};
#pragma unroll
    for (int mf = 0; mf < 4; ++mf)
#pragma unroll
        for (int nf = 0; nf < 4; ++nf)
            acc[mf][nf] = __builtin_amdgcn_mfma_f32_16x16x32_fp8_fp8(
                ax[mf], bx[nf], acc[mf][nf], 0, 0, 0);
#pragma unroll
    for (int mf = 0; mf < 4; ++mf)
#pragma unroll
        for (int nf = 0; nf < 4; ++nf)
            acc[mf][nf] = __builtin_amdgcn_mfma_f32_16x16x32_fp8_fp8(
                ay[mf], by[nf], acc[mf][nf], 0, 0, 0);
}

// ---- Kernel 2: fp8 128^2 upper-tri tile, no LDS, explicit reg dbuf ----------
// R13 counters: MFMA 38% + L2 36% + VALU 27% ~= 100% of wall -> pipes run
// back-to-back (compiler didn't pipeline across kt). Fix: manual 2-deep
// register double-buffer with NAMED fragment vars (rule 20), fully unrolled:
// LOAD(B,kt+1); STEP(A); LOAD(A,kt+2); STEP(B). Loads issue before the 32-MFMA
// cluster; counted vmcnt lets ~620 cyc of MFMA cover L2 latency per kt.
__global__ __launch_bounds__(256, 3) void k_maxdot(const uint8_t* __restrict__ XnT,
                                                   unsigned long long* __restrict__ nn64) {
    const int tid  = threadIdx.x;
    const int lane = tid & 63, wid = tid >> 6;
    const int wr = wid >> 1, wc = wid & 1;
    const int l15 = lane & 15, lhi = lane >> 4;

    // XCD-chunked bijective swizzle (NTILES % 8 == 0)
    int t = (int)blockIdx.x;
    t = (t & 7) * (NTILES / 8) + (t >> 3);
    // decode tile id -> (rb, cb), cb >= rb   [S(rb) = rb*(257-rb)/2]
    float disc = 66049.0f - 8.0f * (float)t;
    int rb = (int)((257.0f - sqrtf(disc)) * 0.5f);
    if (rb > NB - 1) rb = NB - 1;
    if (rb < 0) rb = 0;
    while (rb > 0 && rb * (257 - rb) / 2 > t) --rb;
    while ((rb + 1) * (257 - (rb + 1)) / 2 <= t) ++rb;
    const int cb = rb + (t - rb * (257 - rb) / 2);
    const int rowbase = rb * BM;
    const int colbase = cb * BM;
    const bool diag = (rb == cb);

    const uint8_t* pA = XnT + (size_t)rb * NQ * 128 * 16;
    const uint8_t* pB = XnT + (size_t)cb * NQ * 128 * 16;

    f32x4 acc[4][4];
    const f32x4 z = {0.f, 0.f, 0.f, 0.f};
#pragma unroll
    for (int i = 0; i < 4; ++i)
#pragma unroll
        for (int j = 0; j < 4; ++j) acc[i][j] = z;

    const int arow = wr * 64 + l15;
    const int brow = wc * 64 + l15;

    long2_t aA0, aA1, aA2, aA3, bA0, bA1, bA2, bA3;
    long2_t aB0, aB1, aB2, aB3, bB0, bB1, bB2, bB3;

#define LOADN(P, KT) do {                                                   \
        const size_t qo_ = (size_t)((KT) * 4 + lhi) * 2048;                 \
        a##P##0 = *(const long2_t*)(pA + qo_ + (size_t)(arow     ) * 16);   \
        a##P##1 = *(const long2_t*)(pA + qo_ + (size_t)(arow + 16) * 16);   \
        a##P##2 = *(const long2_t*)(pA + qo_ + (size_t)(arow + 32) * 16);   \
        a##P##3 = *(const long2_t*)(pA + qo_ + (size_t)(arow + 48) * 16);   \
        b##P##0 = *(const long2_t*)(pB + qo_ + (size_t)(brow     ) * 16);   \
        b##P##1 = *(const long2_t*)(pB + qo_ + (size_t)(brow + 16) * 16);   \
        b##P##2 = *(const long2_t*)(pB + qo_ + (size_t)(brow + 32) * 16);   \
        b##P##3 = *(const long2_t*)(pB + qo_ + (size_t)(brow + 48) * 16);   \
    } while (0)

    LOADN(A, 0);
#pragma unroll
    for (int kt2 = 0; kt2 < 6; ++kt2) {
        LOADN(B, kt2 * 2 + 1);
        mstep(acc, aA0, aA1, aA2, aA3, bA0, bA1, bA2, bA3);
        if (kt2 < 5) LOADN(A, kt2 * 2 + 2);
        mstep(acc, aB0, aB1, aB2, aB3, bB0, bB1, bB2, bB3);
    }
#undef LOADN

    // diagonal tiles: mask self-similarity to -1 (reference semantics)
    if (diag) {
#pragma unroll
        for (int mf = 0; mf < 4; ++mf)
#pragma unroll
            for (int nf = 0; nf < 4; ++nf)
#pragma unroll
                for (int rr = 0; rr < 4; ++rr) {
                    const int rl = wr * 64 + mf * 16 + lhi * 4 + rr;
                    const int cl = wc * 64 + nf * 16 + l15;
                    if (rl == cl) acc[mf][nf][rr] = -1.0f;
                }
    }

    // ---- row-max with argmax col: nf regs -> 16 cols (lane bits 0..3) ----
#pragma unroll
    for (int mf = 0; mf < 4; ++mf)
#pragma unroll
        for (int rr = 0; rr < 4; ++rr) {
            float v = acc[mf][0][rr];
            int   c = colbase + wc * 64 + l15;
#pragma unroll
            for (int nf = 1; nf < 4; ++nf) {
                const float w2 = acc[mf][nf][rr];
                const int   c2 = colbase + wc * 64 + nf * 16 + l15;
                if (w2 > v) { v = w2; c = c2; }
            }
#pragma unroll
            for (int m = 1; m <= 8; m <<= 1) {
                const float ov = __shfl_xor(v, m);
                const int   oc = __shfl_xor(c, m);
                if (ov > v) { v = ov; c = oc; }
            }
            if (l15 == 0) {
                const int r = rowbase + wr * 64 + mf * 16 + lhi * 4 + rr;
                atomicMax(&nn64[r], pack_vc(v, c));
            }
        }

    // ---- col-max with argmax row: mf,rr regs -> row-groups (bits 4,5) ----
#pragma unroll
    for (int nf = 0; nf < 4; ++nf) {
        float v = acc[0][nf][0];
        int   c = rowbase + wr * 64 + lhi * 4;
#pragma unroll
        for (int mf = 0; mf < 4; ++mf)
#pragma unroll
            for (int rr = 0; rr < 4; ++rr) {
                if (mf == 0 && rr == 0) continue;
                const float w2 = acc[mf][nf][rr];
                const int   c2 = rowbase + wr * 64 + mf * 16 + lhi * 4 + rr;
                if (w2 > v) { v = w2; c = c2; }
            }
#pragma unroll
        for (int m = 16; m <= 32; m <<= 1) {
            const float ov = __shfl_xor(v, m);
            const int   oc = __shfl_xor(c, m);
            if (ov > v) { v = ov; c = oc; }
        }
        if ((lane >> 4) == 0) {
            const int cc = colbase + wc * 64 + nf * 16 + l15;
            atomicMax(&nn64[cc], pack_vc(v, c));
        }
    }
}

// --- Kernel 3: fp32 exact refine — reference distance for selected neighbor --
__global__ __launch_bounds__(256) void k_refine(const float* __restrict__ X,
                                                const float* __restrict__ norms,
                                                const unsigned long long* __restrict__ nn64,
                                                float* __restrict__ logd) {
    const int wid = threadIdx.x >> 6, lane = threadIdx.x & 63;
    const int r = blockIdx.x * 4 + wid;
    const int j = (int)(nn64[r] & 0xFFFFu);
    const float rnr = 1.0f / fmaxf(norms[r], KEPS);
    const float rnj = 1.0f / fmaxf(norms[j], KEPS);
    const float4* xr = (const float4*)(X + (size_t)r * DIM) + lane * 3;
    const float4* xj = (const float4*)(X + (size_t)j * DIM) + lane * 3;
    float s = 0.0f;
#pragma unroll
    for (int i = 0; i < 3; ++i) {
        const float4 a = xr[i], b = xj[i];
        float d;
        d = a.x * rnr - b.x * rnj + KEPS; s = fmaf(d, d, s);
        d = a.y * rnr - b.y * rnj + KEPS; s = fmaf(d, d, s);
        d = a.z * rnr - b.z * rnj + KEPS; s = fmaf(d, d, s);
        d = a.w * rnr - b.w * rnj + KEPS; s = fmaf(d, d, s);
    }
#pragma unroll
    for (int m = 32; m >= 1; m >>= 1) s += __shfl_xor(s, m);
    if (lane == 0) logd[r] = logf(sqrtf(s) + KEPS);
}

// ---------------- Kernel 4: deterministic mean of log-distances --------------
__global__ __launch_bounds__(256) void k_loss(const float* __restrict__ logd,
                                              float* __restrict__ out) {
    float local = 0.0f;
    for (int r = threadIdx.x; r < NR; r += 256) local += logd[r];
#pragma unroll
    for (int m = 32; m >= 1; m >>= 1) local += __shfl_xor(local, m);
    __shared__ float red[4];
    const int lane = threadIdx.x & 63, wid = threadIdx.x >> 6;
    if (lane == 0) red[wid] = local;
    __syncthreads();
    if (threadIdx.x == 0)
        out[0] = -(red[0] + red[1] + red[2] + red[3]) / (float)NR;
}

extern "C" void kernel_launch(void* const* d_in, const int* in_sizes, int n_in,
                              void* d_out, int out_size, void* d_ws, size_t ws_size,
                              hipStream_t stream) {
    const float* X = (const float*)d_in[0];
    float* out = (float*)d_out;
    uint8_t* XnT = (uint8_t*)d_ws;                                 // 12.6 MiB fp8 (transposed)
    char* p = (char*)d_ws + (size_t)NR * DIM;
    float* norms = (float*)p;                 p += (size_t)NR * 4;
    unsigned long long* nn64 = (unsigned long long*)p; p += (size_t)NR * 8;
    float* logd = (float*)p;

    k_norm<<<NR / 64, 256, 0, stream>>>(X, XnT, norms);
    k_init<<<NR / 256, 256, 0, stream>>>(nn64);
    k_maxdot<<<NTILES, 256, 0, stream>>>(XnT, nn64);
    k_refine<<<NR / 4, 256, 0, stream>>>(X, norms, nn64, logd);
    k_loss<<<1, 256, 0, stream>>>(logd, out);
}

// Round 15
// 307.545 us; speedup vs baseline: 1.4034x; 1.4034x over previous
//
#include <hip/hip_runtime.h>
#include <hip/hip_bf16.h>
#include <stdint.h>
#include <math.h>

#define NR 16384
#define DIM 768
#define KEPS 1e-8f

#define BM 128          // tile edge
#define NB (NR / BM)    // 128 row/col panels
#define KT (DIM / 64)   // 12 k-steps of 64
#define NQ (DIM / 16)   // 48 16B chunks per row
#define NTILES (NB * (NB + 1) / 2)   // 8256 upper-triangle tiles

typedef __attribute__((ext_vector_type(4))) float f32x4;
typedef __attribute__((ext_vector_type(2))) long long2_t;

__device__ inline uint32_t fkey(float f) {
    union { float f; uint32_t u; } v; v.f = f;
    return (v.u & 0x80000000u) ? ~v.u : (v.u | 0x80000000u);
}

__device__ inline unsigned long long pack_vc(float v, int c) {
    return ((unsigned long long)fkey(v) << 32) | (unsigned)c;
}

// fp32 -> OCP e4m3fn (selection only; refine pass recomputes exact fp32)
__device__ inline uint8_t f2fp8(float f) {
    union { float f; uint32_t u; } v; v.f = f;
    const uint8_t s = (uint8_t)((v.u >> 24) & 0x80u);
    float a = fabsf(f);
    if (a >= 448.0f) return s | 0x7E;
    if (a < 0.015625f) {
        int q = (int)rintf(a * 512.0f);
        if (q >= 8) return s | 0x08;
        return s | (uint8_t)q;
    }
    int ex; float m = frexpf(a, &ex);
    int E = ex + 6;
    int frac = (int)rintf(m * 16.0f - 8.0f);
    if (frac >= 8) { frac = 0; ++E; if (E > 15) return s | 0x7E; }
    return s | (uint8_t)(E << 3) | (uint8_t)frac;
}

// ---- Kernel 1: L2-normalize -> fp8, write panel-blocked TRANSPOSED layout ---
// (R13 version, proven) XnT[panel p][chunk q 0..47][row r 0..127]: 16B chunks;
// ks-pairing permutation (orig byte ks*32+h*8+b -> h*16+ks*8+b) per 64-k block
// so one global_load_dwordx4 delivers a lane's ks0+ks1 MFMA fragments.
__global__ __launch_bounds__(256) void k_norm(const float* __restrict__ X,
                                              uint8_t* __restrict__ XnT,
                                              float* __restrict__ norms) {
    __shared__ uint8_t buf[4][768];
    const int wid = threadIdx.x >> 6, lane = threadIdx.x & 63;
    const int row = blockIdx.x * 4 + wid;
    const float4* xr = (const float4*)(X + (size_t)row * DIM) + lane * 3;
    float4 a = xr[0], b = xr[1], c = xr[2];
    float s = a.x*a.x + a.y*a.y + a.z*a.z + a.w*a.w
            + b.x*b.x + b.y*b.y + b.z*b.z + b.w*b.w
            + c.x*c.x + c.y*c.y + c.z*c.z + c.w*c.w;
#pragma unroll
    for (int m = 32; m >= 1; m >>= 1) s += __shfl_xor(s, m);
    const float n = sqrtf(s);
    if (lane == 0) norms[row] = n;
    const float rn = 1.0f / fmaxf(n, KEPS);
    float v[12] = {a.x,a.y,a.z,a.w,b.x,b.y,b.z,b.w,c.x,c.y,c.z,c.w};
    uint8_t q[12];
#pragma unroll
    for (int i = 0; i < 12; ++i) q[i] = f2fp8(v[i] * rn);
    uint32_t* lb = (uint32_t*)&buf[wid][lane * 12];
    lb[0] = (uint32_t)q[0] | ((uint32_t)q[1] << 8) | ((uint32_t)q[2]  << 16) | ((uint32_t)q[3]  << 24);
    lb[1] = (uint32_t)q[4] | ((uint32_t)q[5] << 8) | ((uint32_t)q[6]  << 16) | ((uint32_t)q[7]  << 24);
    lb[2] = (uint32_t)q[8] | ((uint32_t)q[9] << 8) | ((uint32_t)q[10] << 16) | ((uint32_t)q[11] << 24);
    __syncthreads();
    if (lane < NQ) {
        const int blk = lane >> 2;       // 64-k block 0..11
        const int h   = lane & 3;        // 8-k group within 32-k half
        const uint2 lo = *(const uint2*)&buf[wid][blk * 64 + h * 8];        // ks=0
        const uint2 hi = *(const uint2*)&buf[wid][blk * 64 + 32 + h * 8];   // ks=1
        const size_t off = ((size_t)(row >> 7) * NQ * 128 + (size_t)lane * 128
                            + (row & 127)) * 16;
        *(uint4*)(XnT + off) = make_uint4(lo.x, lo.y, hi.x, hi.y);
    }
}

// ---------------- Kernel 1b: init (value, index) max keys --------------------
__global__ __launch_bounds__(256) void k_init(unsigned long long* __restrict__ nn64) {
    nn64[blockIdx.x * 256 + threadIdx.x] = pack_vc(-2.0f, 0);
}

// ---- Kernel 2: fp8 128^2 upper-tri tile, NO LDS / NO barriers ---------------
// R13 structure (best measured: 259us, MfmaUtil 33%). Single delta:
// __launch_bounds__(256,4) holds the allocator to <=128 unified regs so 4
// blocks/CU co-reside (was ~3) -> more independent waves cover the ~575cyc/kt
// L2-latency term that MFMA+VALU don't.
__global__ __launch_bounds__(256, 4) void k_maxdot(const uint8_t* __restrict__ XnT,
                                                   unsigned long long* __restrict__ nn64) {
    const int tid  = threadIdx.x;
    const int lane = tid & 63, wid = tid >> 6;
    const int wr = wid >> 1, wc = wid & 1;
    const int l15 = lane & 15, lhi = lane >> 4;

    // XCD-chunked bijective swizzle (NTILES % 8 == 0)
    int t = (int)blockIdx.x;
    t = (t & 7) * (NTILES / 8) + (t >> 3);
    // decode tile id -> (rb, cb), cb >= rb   [S(rb) = rb*(257-rb)/2]
    float disc = 66049.0f - 8.0f * (float)t;
    int rb = (int)((257.0f - sqrtf(disc)) * 0.5f);
    if (rb > NB - 1) rb = NB - 1;
    if (rb < 0) rb = 0;
    while (rb > 0 && rb * (257 - rb) / 2 > t) --rb;
    while ((rb + 1) * (257 - (rb + 1)) / 2 <= t) ++rb;
    const int cb = rb + (t - rb * (257 - rb) / 2);
    const int rowbase = rb * BM;
    const int colbase = cb * BM;
    const bool diag = (rb == cb);

    // panel bases in the transposed layout (panel index == rb/cb)
    const uint8_t* pA = XnT + (size_t)rb * NQ * 128 * 16;
    const uint8_t* pB = XnT + (size_t)cb * NQ * 128 * 16;

    f32x4 acc[4][4];
    const f32x4 z = {0.f, 0.f, 0.f, 0.f};
#pragma unroll
    for (int i = 0; i < 4; ++i)
#pragma unroll
        for (int j = 0; j < 4; ++j) acc[i][j] = z;

    // per kt: chunk q = kt*4 + lhi; fragment addr = panel + (q*128 + row)*16
    const int arow = wr * 64 + l15;     // + mf*16
    const int brow = wc * 64 + l15;     // + nf*16
#pragma unroll 2
    for (int kt = 0; kt < KT; ++kt) {
        const size_t qoff = (size_t)(kt * 4 + lhi) * 128 * 16;
        long2_t af[4], bg[4];
#pragma unroll
        for (int mf = 0; mf < 4; ++mf)
            af[mf] = *(const long2_t*)(pA + qoff + (size_t)(arow + mf * 16) * 16);
#pragma unroll
        for (int nf = 0; nf < 4; ++nf)
            bg[nf] = *(const long2_t*)(pB + qoff + (size_t)(brow + nf * 16) * 16);
#pragma unroll
        for (int mf = 0; mf < 4; ++mf)
#pragma unroll
            for (int nf = 0; nf < 4; ++nf)
                acc[mf][nf] = __builtin_amdgcn_mfma_f32_16x16x32_fp8_fp8(
                    af[mf].x, bg[nf].x, acc[mf][nf], 0, 0, 0);
#pragma unroll
        for (int mf = 0; mf < 4; ++mf)
#pragma unroll
            for (int nf = 0; nf < 4; ++nf)
                acc[mf][nf] = __builtin_amdgcn_mfma_f32_16x16x32_fp8_fp8(
                    af[mf].y, bg[nf].y, acc[mf][nf], 0, 0, 0);
    }

    // diagonal tiles: mask self-similarity to -1 (reference semantics)
    if (diag) {
#pragma unroll
        for (int mf = 0; mf < 4; ++mf)
#pragma unroll
            for (int nf = 0; nf < 4; ++nf)
#pragma unroll
                for (int rr = 0; rr < 4; ++rr) {
                    const int rl = wr * 64 + mf * 16 + lhi * 4 + rr;
                    const int cl = wc * 64 + nf * 16 + l15;
                    if (rl == cl) acc[mf][nf][rr] = -1.0f;
                }
    }

    // ---- row-max with argmax col: nf regs -> 16 cols (lane bits 0..3) ----
#pragma unroll
    for (int mf = 0; mf < 4; ++mf)
#pragma unroll
        for (int rr = 0; rr < 4; ++rr) {
            float v = acc[mf][0][rr];
            int   c = colbase + wc * 64 + l15;
#pragma unroll
            for (int nf = 1; nf < 4; ++nf) {
                const float w2 = acc[mf][nf][rr];
                const int   c2 = colbase + wc * 64 + nf * 16 + l15;
                if (w2 > v) { v = w2; c = c2; }
            }
#pragma unroll
            for (int m = 1; m <= 8; m <<= 1) {
                const float ov = __shfl_xor(v, m);
                const int   oc = __shfl_xor(c, m);
                if (ov > v) { v = ov; c = oc; }
            }
            if (l15 == 0) {
                const int r = rowbase + wr * 64 + mf * 16 + lhi * 4 + rr;
                atomicMax(&nn64[r], pack_vc(v, c));
            }
        }

    // ---- col-max with argmax row: mf,rr regs -> row-groups (bits 4,5) ----
#pragma unroll
    for (int nf = 0; nf < 4; ++nf) {
        float v = acc[0][nf][0];
        int   c = rowbase + wr * 64 + lhi * 4;
#pragma unroll
        for (int mf = 0; mf < 4; ++mf)
#pragma unroll
            for (int rr = 0; rr < 4; ++rr) {
                if (mf == 0 && rr == 0) continue;
                const float w2 = acc[mf][nf][rr];
                const int   c2 = rowbase + wr * 64 + mf * 16 + lhi * 4 + rr;
                if (w2 > v) { v = w2; c = c2; }
            }
#pragma unroll
        for (int m = 16; m <= 32; m <<= 1) {
            const float ov = __shfl_xor(v, m);
            const int   oc = __shfl_xor(c, m);
            if (ov > v) { v = ov; c = oc; }
        }
        if ((lane >> 4) == 0) {
            const int cc = colbase + wc * 64 + nf * 16 + l15;
            atomicMax(&nn64[cc], pack_vc(v, c));
        }
    }
}

// --- Kernel 3: fp32 exact refine — reference distance for selected neighbor --
__global__ __launch_bounds__(256) void k_refine(const float* __restrict__ X,
                                                const float* __restrict__ norms,
                                                const unsigned long long* __restrict__ nn64,
                                                float* __restrict__ logd) {
    const int wid = threadIdx.x >> 6, lane = threadIdx.x & 63;
    const int r = blockIdx.x * 4 + wid;
    const int j = (int)(nn64[r] & 0xFFFFu);
    const float rnr = 1.0f / fmaxf(norms[r], KEPS);
    const float rnj = 1.0f / fmaxf(norms[j], KEPS);
    const float4* xr = (const float4*)(X + (size_t)r * DIM) + lane * 3;
    const float4* xj = (const float4*)(X + (size_t)j * DIM) + lane * 3;
    float s = 0.0f;
#pragma unroll
    for (int i = 0; i < 3; ++i) {
        const float4 a = xr[i], b = xj[i];
        float d;
        d = a.x * rnr - b.x * rnj + KEPS; s = fmaf(d, d, s);
        d = a.y * rnr - b.y * rnj + KEPS; s = fmaf(d, d, s);
        d = a.z * rnr - b.z * rnj + KEPS; s = fmaf(d, d, s);
        d = a.w * rnr - b.w * rnj + KEPS; s = fmaf(d, d, s);
    }
#pragma unroll
    for (int m = 32; m >= 1; m >>= 1) s += __shfl_xor(s, m);
    if (lane == 0) logd[r] = logf(sqrtf(s) + KEPS);
}

// ---------------- Kernel 4: deterministic mean of log-distances --------------
__global__ __launch_bounds__(256) void k_loss(const float* __restrict__ logd,
                                              float* __restrict__ out) {
    float local = 0.0f;
    for (int r = threadIdx.x; r < NR; r += 256) local += logd[r];
#pragma unroll
    for (int m = 32; m >= 1; m >>= 1) local += __shfl_xor(local, m);
    __shared__ float red[4];
    const int lane = threadIdx.x & 63, wid = threadIdx.x >> 6;
    if (lane == 0) red[wid] = local;
    __syncthreads();
    if (threadIdx.x == 0)
        out[0] = -(red[0] + red[1] + red[2] + red[3]) / (float)NR;
}

extern "C" void kernel_launch(void* const* d_in, const int* in_sizes, int n_in,
                              void* d_out, int out_size, void* d_ws, size_t ws_size,
                              hipStream_t stream) {
    const float* X = (const float*)d_in[0];
    float* out = (float*)d_out;
    uint8_t* XnT = (uint8_t*)d_ws;                                 // 12.6 MiB fp8 (transposed)
    char* p = (char*)d_ws + (size_t)NR * DIM;
    float* norms = (float*)p;                 p += (size_t)NR * 4;
    unsigned long long* nn64 = (unsigned long long*)p; p += (size_t)NR * 8;
    float* logd = (float*)p;

    k_norm<<<NR / 4, 256, 0, stream>>>(X, XnT, norms);
    k_init<<<NR / 256, 256, 0, stream>>>(nn64);
    k_maxdot<<<NTILES, 256, 0, stream>>>(XnT, nn64);
    k_refine<<<NR / 4, 256, 0, stream>>>(X, norms, nn64, logd);
    k_loss<<<1, 256, 0, stream>>>(logd, out);
}

// Round 16
// 299.680 us; speedup vs baseline: 1.4403x; 1.0262x over previous
//
#include <hip/hip_runtime.h>
#include <hip/hip_bf16.h>
#include <stdint.h>
#include <math.h>

#define NR 16384
#define DIM 768
#define KEPS 1e-8f

#define NB 128          // 128-row panels in XnT layout
#define KT (DIM / 64)   // 12 k-steps of 64
#define NQ (DIM / 16)   // 48 16B chunks per row
#define NTILES 4160     // rect upper-tri: sum_{rb<64}(128-2rb)

typedef __attribute__((ext_vector_type(4))) float f32x4;
typedef __attribute__((ext_vector_type(2))) long long2_t;

__device__ inline uint32_t fkey(float f) {
    union { float f; uint32_t u; } v; v.f = f;
    return (v.u & 0x80000000u) ? ~v.u : (v.u | 0x80000000u);
}

__device__ inline unsigned long long pack_vc(float v, int c) {
    return ((unsigned long long)fkey(v) << 32) | (unsigned)c;
}

// fp32 -> OCP e4m3fn (selection only; refine pass recomputes exact fp32)
__device__ inline uint8_t f2fp8(float f) {
    union { float f; uint32_t u; } v; v.f = f;
    const uint8_t s = (uint8_t)((v.u >> 24) & 0x80u);
    float a = fabsf(f);
    if (a >= 448.0f) return s | 0x7E;
    if (a < 0.015625f) {
        int q = (int)rintf(a * 512.0f);
        if (q >= 8) return s | 0x08;
        return s | (uint8_t)q;
    }
    int ex; float m = frexpf(a, &ex);
    int E = ex + 6;
    int frac = (int)rintf(m * 16.0f - 8.0f);
    if (frac >= 8) { frac = 0; ++E; if (E > 15) return s | 0x7E; }
    return s | (uint8_t)(E << 3) | (uint8_t)frac;
}

// ---- Kernel 1: L2-normalize -> fp8, write panel-blocked TRANSPOSED layout ---
// (R13 version, proven) XnT[panel p][chunk q 0..47][row r 0..127]: 16B chunks;
// ks-pairing permutation (orig byte ks*32+h*8+b -> h*16+ks*8+b) per 64-k block
// so one global_load_dwordx4 delivers a lane's ks0+ks1 MFMA fragments.
__global__ __launch_bounds__(256) void k_norm(const float* __restrict__ X,
                                              uint8_t* __restrict__ XnT,
                                              float* __restrict__ norms) {
    __shared__ uint8_t buf[4][768];
    const int wid = threadIdx.x >> 6, lane = threadIdx.x & 63;
    const int row = blockIdx.x * 4 + wid;
    const float4* xr = (const float4*)(X + (size_t)row * DIM) + lane * 3;
    float4 a = xr[0], b = xr[1], c = xr[2];
    float s = a.x*a.x + a.y*a.y + a.z*a.z + a.w*a.w
            + b.x*b.x + b.y*b.y + b.z*b.z + b.w*b.w
            + c.x*c.x + c.y*c.y + c.z*c.z + c.w*c.w;
#pragma unroll
    for (int m = 32; m >= 1; m >>= 1) s += __shfl_xor(s, m);
    const float n = sqrtf(s);
    if (lane == 0) norms[row] = n;
    const float rn = 1.0f / fmaxf(n, KEPS);
    float v[12] = {a.x,a.y,a.z,a.w,b.x,b.y,b.z,b.w,c.x,c.y,c.z,c.w};
    uint8_t q[12];
#pragma unroll
    for (int i = 0; i < 12; ++i) q[i] = f2fp8(v[i] * rn);
    uint32_t* lb = (uint32_t*)&buf[wid][lane * 12];
    lb[0] = (uint32_t)q[0] | ((uint32_t)q[1] << 8) | ((uint32_t)q[2]  << 16) | ((uint32_t)q[3]  << 24);
    lb[1] = (uint32_t)q[4] | ((uint32_t)q[5] << 8) | ((uint32_t)q[6]  << 16) | ((uint32_t)q[7]  << 24);
    lb[2] = (uint32_t)q[8] | ((uint32_t)q[9] << 8) | ((uint32_t)q[10] << 16) | ((uint32_t)q[11] << 24);
    __syncthreads();
    if (lane < NQ) {
        const int blk = lane >> 2;       // 64-k block 0..11
        const int h   = lane & 3;        // 8-k group within 32-k half
        const uint2 lo = *(const uint2*)&buf[wid][blk * 64 + h * 8];        // ks=0
        const uint2 hi = *(const uint2*)&buf[wid][blk * 64 + 32 + h * 8];   // ks=1
        const size_t off = ((size_t)(row >> 7) * NQ * 128 + (size_t)lane * 128
                            + (row & 127)) * 16;
        *(uint4*)(XnT + off) = make_uint4(lo.x, lo.y, hi.x, hi.y);
    }
}

// ---------------- Kernel 1b: init (value, index) max keys --------------------
__global__ __launch_bounds__(256) void k_init(unsigned long long* __restrict__ nn64) {
    nn64[blockIdx.x * 256 + threadIdx.x] = pack_vc(-2.0f, 0);
}

// ---- Kernel 2: fp8 256x128 upper-tri tile, 128x64 wave tile, no LDS ---------
// R13-R15 audit: MFMA 37%, L2 34%, VALU 27%, HBM 4% -> latency structure, no
// saturated pipe. This round: 2x per-wave arithmetic intensity. Wave = 128x64
// (acc[8][4], 128 AGPR): 12 loads cover 64 MFMA (was 8/32) -> load-instr,
// addr-VALU, L2 request bytes per MFMA all -25%, and each load-wait hides
// under a 2x MFMA burst. Trade: 2 waves/SIMD (TLP) for ILP - the bracket
// complement of R15's TLP-up null. Rect tiles (rb,cb): rows rb*256..+256,
// cols cb*128..+128, cb>=2rb; S(rb)=rb*(129-rb); max idempotent => overlap
// below the diagonal is harmless, only rl==cl masked.
__global__ __launch_bounds__(256, 2) void k_maxdot(const uint8_t* __restrict__ XnT,
                                                   unsigned long long* __restrict__ nn64) {
    const int tid  = threadIdx.x;
    const int lane = tid & 63, wid = tid >> 6;
    const int wr = wid >> 1, wc = wid & 1;
    const int l15 = lane & 15, lhi = lane >> 4;

    // XCD-chunked bijective swizzle (NTILES % 8 == 0)
    int t = (int)blockIdx.x;
    t = (t & 7) * (NTILES / 8) + (t >> 3);
    // decode tile id -> (rb, cb): S(rb) = rb*(129-rb), cb = 2rb + (t - S(rb))
    int rb = (int)((129.0f - sqrtf(16641.0f - 4.0f * (float)t)) * 0.5f);
    if (rb < 0) rb = 0;
    if (rb > 63) rb = 63;
    while (rb > 0 && rb * (129 - rb) > t) --rb;
    while ((rb + 1) * (129 - (rb + 1)) <= t) ++rb;
    const int cb = 2 * rb + (t - rb * (129 - rb));

    // wave's A panel: rows rb*256 + wr*128 (one full 128-row XnT panel)
    const uint8_t* pA = XnT + (size_t)(2 * rb + wr) * NQ * 128 * 16;
    // wave's B cols: panel cb, rows wc*64 + nf*16 + l15
    const uint8_t* pB = XnT + (size_t)cb * NQ * 128 * 16;
    const int rowbase = rb * 256 + wr * 128;   // wave's global row base
    const int colbase = cb * 128 + wc * 64;    // wave's global col base
    const bool maybe_diag = (cb == 2 * rb) || (cb == 2 * rb + 1);

    f32x4 acc[8][4];
    const f32x4 z = {0.f, 0.f, 0.f, 0.f};
#pragma unroll
    for (int i = 0; i < 8; ++i)
#pragma unroll
        for (int j = 0; j < 4; ++j) acc[i][j] = z;

    const int arow = l15;              // + mf*16 (within pA panel)
    const int brow = wc * 64 + l15;    // + nf*16 (within pB panel)
#pragma unroll 2
    for (int kt = 0; kt < KT; ++kt) {
        const size_t qoff = (size_t)(kt * 4 + lhi) * 128 * 16;
        long2_t af[8], bg[4];
#pragma unroll
        for (int mf = 0; mf < 8; ++mf)
            af[mf] = *(const long2_t*)(pA + qoff + (size_t)(arow + mf * 16) * 16);
#pragma unroll
        for (int nf = 0; nf < 4; ++nf)
            bg[nf] = *(const long2_t*)(pB + qoff + (size_t)(brow + nf * 16) * 16);
#pragma unroll
        for (int mf = 0; mf < 8; ++mf)
#pragma unroll
            for (int nf = 0; nf < 4; ++nf)
                acc[mf][nf] = __builtin_amdgcn_mfma_f32_16x16x32_fp8_fp8(
                    af[mf].x, bg[nf].x, acc[mf][nf], 0, 0, 0);
#pragma unroll
        for (int mf = 0; mf < 8; ++mf)
#pragma unroll
            for (int nf = 0; nf < 4; ++nf)
                acc[mf][nf] = __builtin_amdgcn_mfma_f32_16x16x32_fp8_fp8(
                    af[mf].y, bg[nf].y, acc[mf][nf], 0, 0, 0);
    }

    // mask self-similarity (rl == cl) to -1 on diagonal-crossing tiles
    if (maybe_diag) {
#pragma unroll
        for (int mf = 0; mf < 8; ++mf)
#pragma unroll
            for (int nf = 0; nf < 4; ++nf)
#pragma unroll
                for (int rr = 0; rr < 4; ++rr) {
                    const int rl = rowbase + mf * 16 + lhi * 4 + rr;
                    const int cl = colbase + nf * 16 + l15;
                    if (rl == cl) acc[mf][nf][rr] = -1.0f;
                }
    }

    // ---- row-max with argmax col: nf regs -> 16 cols (lane bits 0..3) ----
#pragma unroll
    for (int mf = 0; mf < 8; ++mf)
#pragma unroll
        for (int rr = 0; rr < 4; ++rr) {
            float v = acc[mf][0][rr];
            int   c = colbase + l15;
#pragma unroll
            for (int nf = 1; nf < 4; ++nf) {
                const float w2 = acc[mf][nf][rr];
                const int   c2 = colbase + nf * 16 + l15;
                if (w2 > v) { v = w2; c = c2; }
            }
#pragma unroll
            for (int m = 1; m <= 8; m <<= 1) {
                const float ov = __shfl_xor(v, m);
                const int   oc = __shfl_xor(c, m);
                if (ov > v) { v = ov; c = oc; }
            }
            if (l15 == 0) {
                const int r = rowbase + mf * 16 + lhi * 4 + rr;
                atomicMax(&nn64[r], pack_vc(v, c));
            }
        }

    // ---- col-max with argmax row: mf,rr regs -> row-groups (bits 4,5) ----
#pragma unroll
    for (int nf = 0; nf < 4; ++nf) {
        float v = acc[0][nf][0];
        int   c = rowbase + lhi * 4;
#pragma unroll
        for (int mf = 0; mf < 8; ++mf)
#pragma unroll
            for (int rr = 0; rr < 4; ++rr) {
                if (mf == 0 && rr == 0) continue;
                const float w2 = acc[mf][nf][rr];
                const int   c2 = rowbase + mf * 16 + lhi * 4 + rr;
                if (w2 > v) { v = w2; c = c2; }
            }
#pragma unroll
        for (int m = 16; m <= 32; m <<= 1) {
            const float ov = __shfl_xor(v, m);
            const int   oc = __shfl_xor(c, m);
            if (ov > v) { v = ov; c = oc; }
        }
        if ((lane >> 4) == 0) {
            const int cc = colbase + nf * 16 + l15;
            atomicMax(&nn64[cc], pack_vc(v, c));
        }
    }
}

// --- Kernel 3: fp32 exact refine — reference distance for selected neighbor --
__global__ __launch_bounds__(256) void k_refine(const float* __restrict__ X,
                                                const float* __restrict__ norms,
                                                const unsigned long long* __restrict__ nn64,
                                                float* __restrict__ logd) {
    const int wid = threadIdx.x >> 6, lane = threadIdx.x & 63;
    const int r = blockIdx.x * 4 + wid;
    const int j = (int)(nn64[r] & 0xFFFFu);
    const float rnr = 1.0f / fmaxf(norms[r], KEPS);
    const float rnj = 1.0f / fmaxf(norms[j], KEPS);
    const float4* xr = (const float4*)(X + (size_t)r * DIM) + lane * 3;
    const float4* xj = (const float4*)(X + (size_t)j * DIM) + lane * 3;
    float s = 0.0f;
#pragma unroll
    for (int i = 0; i < 3; ++i) {
        const float4 a = xr[i], b = xj[i];
        float d;
        d = a.x * rnr - b.x * rnj + KEPS; s = fmaf(d, d, s);
        d = a.y * rnr - b.y * rnj + KEPS; s = fmaf(d, d, s);
        d = a.z * rnr - b.z * rnj + KEPS; s = fmaf(d, d, s);
        d = a.w * rnr - b.w * rnj + KEPS; s = fmaf(d, d, s);
    }
#pragma unroll
    for (int m = 32; m >= 1; m >>= 1) s += __shfl_xor(s, m);
    if (lane == 0) logd[r] = logf(sqrtf(s) + KEPS);
}

// ---------------- Kernel 4: deterministic mean of log-distances --------------
__global__ __launch_bounds__(256) void k_loss(const float* __restrict__ logd,
                                              float* __restrict__ out) {
    float local = 0.0f;
    for (int r = threadIdx.x; r < NR; r += 256) local += logd[r];
#pragma unroll
    for (int m = 32; m >= 1; m >>= 1) local += __shfl_xor(local, m);
    __shared__ float red[4];
    const int lane = threadIdx.x & 63, wid = threadIdx.x >> 6;
    if (lane == 0) red[wid] = local;
    __syncthreads();
    if (threadIdx.x == 0)
        out[0] = -(red[0] + red[1] + red[2] + red[3]) / (float)NR;
}

extern "C" void kernel_launch(void* const* d_in, const int* in_sizes, int n_in,
                              void* d_out, int out_size, void* d_ws, size_t ws_size,
                              hipStream_t stream) {
    const float* X = (const float*)d_in[0];
    float* out = (float*)d_out;
    uint8_t* XnT = (uint8_t*)d_ws;                                 // 12.6 MiB fp8 (transposed)
    char* p = (char*)d_ws + (size_t)NR * DIM;
    float* norms = (float*)p;                 p += (size_t)NR * 4;
    unsigned long long* nn64 = (unsigned long long*)p; p += (size_t)NR * 8;
    float* logd = (float*)p;

    k_norm<<<NR / 4, 256, 0, stream>>>(X, XnT, norms);
    k_init<<<NR / 256, 256, 0, stream>>>(nn64);
    k_maxdot<<<NTILES, 256, 0, stream>>>(XnT, nn64);
    k_refine<<<NR / 4, 256, 0, stream>>>(X, norms, nn64, logd);
    k_loss<<<1, 256, 0, stream>>>(logd, out);
}